// Round 3
// baseline (1881.366 us; speedup 1.0000x reference)
//
#include <hip/hip_runtime.h>
#include <hip/hip_bf16.h>

// Problem constants
#define B_   64
#define N_   512
#define D_   256
#define H_   4
#define HD_  64

typedef __hip_bfloat16 bf16;

__device__ __forceinline__ float bf2f(bf16 v) { return __bfloat162float(v); }
__device__ __forceinline__ float us2f(unsigned short u) {
    union { unsigned int i; float f; } c; c.i = ((unsigned int)u) << 16; return c.f;
}
__device__ __forceinline__ unsigned short f2us(float f) {
    bf16 h = __float2bfloat16(f);
    union { bf16 h; unsigned short u; } c; c.h = h; return c.u;
}

// ---------------------------------------------------------------------------
// Tiled GEMM: C[m][n] = sum_k A[m][k] * W[n][k] (+bias[n]) (relu?) (+res[m][n])
// A: bf16 (ABF16=1, intermediates) or fp32 (ABF16=0, raw inputs).
// W/bias: fp32. res: bf16 or null. C: bf16. fp32 accumulate.
// VEC=1 requires K % 4 == 0. Tile 64x64, BK=16, 256 thr, 4x4 microtile.
// ---------------------------------------------------------------------------
template<int ABF16, int VEC>
__global__ __launch_bounds__(256)
void gemm_k(const void* __restrict__ A_, const float* __restrict__ W,
            const float* __restrict__ bias, const bf16* __restrict__ res,
            bf16* __restrict__ C, int M, int N, int K, int relu)
{
    __shared__ float As[16][68];   // [k][m]
    __shared__ float Ws[16][68];   // [k][n]

    const int tid = threadIdx.x;
    const int m0 = blockIdx.x * 64;
    const int n0 = blockIdx.y * 64;
    const int lr = tid >> 2;          // 0..63 row within tile
    const int lk = (tid & 3) * 4;     // k sub-offset
    const int tx = tid & 15, ty = tid >> 4;

    float acc[4][4] = {};

    for (int k0 = 0; k0 < K; k0 += 16) {
        __syncthreads();
        if (VEC) {
            if (ABF16) {
                const ushort4 a4 = *reinterpret_cast<const ushort4*>(
                    (const unsigned short*)A_ + (size_t)(m0 + lr) * K + k0 + lk);
                As[lk + 0][lr] = us2f(a4.x); As[lk + 1][lr] = us2f(a4.y);
                As[lk + 2][lr] = us2f(a4.z); As[lk + 3][lr] = us2f(a4.w);
            } else {
                const float4 a4 = *reinterpret_cast<const float4*>(
                    (const float*)A_ + (size_t)(m0 + lr) * K + k0 + lk);
                As[lk + 0][lr] = a4.x; As[lk + 1][lr] = a4.y;
                As[lk + 2][lr] = a4.z; As[lk + 3][lr] = a4.w;
            }
            const float4 w4 = *reinterpret_cast<const float4*>(W + (size_t)(n0 + lr) * K + k0 + lk);
            Ws[lk + 0][lr] = w4.x; Ws[lk + 1][lr] = w4.y;
            Ws[lk + 2][lr] = w4.z; Ws[lk + 3][lr] = w4.w;
        } else {
            #pragma unroll
            for (int i = 0; i < 4; ++i) {
                int k = k0 + lk + i;
                float av = 0.f, wv = 0.f;
                if (k < K) {
                    if (ABF16) av = bf2f(((const bf16*)A_)[(size_t)(m0 + lr) * K + k]);
                    else       av = ((const float*)A_)[(size_t)(m0 + lr) * K + k];
                    wv = W[(size_t)(n0 + lr) * K + k];
                }
                As[lk + i][lr] = av;
                Ws[lk + i][lr] = wv;
            }
        }
        __syncthreads();
        #pragma unroll
        for (int kk = 0; kk < 16; ++kk) {
            const float4 a4 = *reinterpret_cast<const float4*>(&As[kk][ty * 4]);
            const float4 b4 = *reinterpret_cast<const float4*>(&Ws[kk][tx * 4]);
            const float av[4] = {a4.x, a4.y, a4.z, a4.w};
            const float bv[4] = {b4.x, b4.y, b4.z, b4.w};
            #pragma unroll
            for (int ii = 0; ii < 4; ++ii)
                #pragma unroll
                for (int jj = 0; jj < 4; ++jj)
                    acc[ii][jj] += av[ii] * bv[jj];
        }
    }

    #pragma unroll
    for (int ii = 0; ii < 4; ++ii) {
        int m = m0 + ty * 4 + ii;
        #pragma unroll
        for (int jj = 0; jj < 4; ++jj) {
            int n = n0 + tx * 4 + jj;
            float v = acc[ii][jj];
            if (bias) v += bias[n];
            if (relu) v = fmaxf(v, 0.f);
            if (res)  v += bf2f(res[(size_t)m * N + n]);
            C[(size_t)m * N + n] = __float2bfloat16(v);
        }
    }
}

// ---------------------------------------------------------------------------
// LayerNorm over last dim (256), bf16 in/out (in-place safe), fp32 g/b,
// optional on-the-fly sinusoidal positional embedding.
// ---------------------------------------------------------------------------
__global__ __launch_bounds__(256)
void ln_k(const bf16* in, bf16* out,
          const float* __restrict__ g, const float* __restrict__ b, int use_pe)
{
    __shared__ float red[256];
    const int row = blockIdx.x;
    const int c = threadIdx.x;
    float v = bf2f(in[(size_t)row * D_ + c]);
    if (use_pe) {
        int n = row & (N_ - 1);
        int j = c & ~1;
        float freq = __expf(-(float)j * (9.210340371976184f / 256.0f)); // ln(10000)/d
        float ang = (float)n * freq;
        v += (c & 1) ? cosf(ang) : sinf(ang);
    }
    red[c] = v; __syncthreads();
    for (int s = 128; s > 0; s >>= 1) { if (c < s) red[c] += red[c + s]; __syncthreads(); }
    float mu = red[0] * (1.f / 256.f);
    __syncthreads();
    float d = v - mu;
    red[c] = d * d; __syncthreads();
    for (int s = 128; s > 0; s >>= 1) { if (c < s) red[c] += red[c + s]; __syncthreads(); }
    float var = red[0] * (1.f / 256.f);
    float rs = rsqrtf(var + 1e-5f);
    out[(size_t)row * D_ + c] = __float2bfloat16(d * rs * g[c] + b[c]);
}

// ---------------------------------------------------------------------------
// Cross-attention, non-causal. One block per (b, h, 16-query tile).
// q,k,v,ctx bf16 (B,N,D), head h at cols [h*64,h*64+64). ctx MAY alias q:
// each block writes exactly its own Q-tile region (staged in LDS first), and
// head slices are disjoint 128B-aligned column ranges.
// ---------------------------------------------------------------------------
__global__ __launch_bounds__(256)
void attn_k(const bf16* q, const bf16* __restrict__ k,
            const bf16* __restrict__ v, bf16* ctx)
{
    constexpr int TQ = 16;
    __shared__ float Qs[TQ][HD_ + 4];      // [qrow][c]
    __shared__ float KVs[64][HD_ + 4];     // K phase: [c][j] transposed; V: [j][c]
    __shared__ float Sc[TQ][N_ + 4];       // scores/probs

    const int tid = threadIdx.x;
    const int qt = blockIdx.x & 31;
    const int h  = (blockIdx.x >> 5) & 3;
    const int b  = blockIdx.x >> 7;
    const int q0 = qt * TQ;
    const size_t base = ((size_t)b * N_) * D_ + h * HD_;

    {
        int r = tid >> 4, c4 = tid & 15;
        ushort4 qa = *reinterpret_cast<const ushort4*>(q + base + (size_t)(q0 + r) * D_ + c4 * 4);
        Qs[r][c4 * 4 + 0] = us2f(qa.x); Qs[r][c4 * 4 + 1] = us2f(qa.y);
        Qs[r][c4 * 4 + 2] = us2f(qa.z); Qs[r][c4 * 4 + 3] = us2f(qa.w);
    }
    const int tx = tid & 15, ty = tid >> 4;

    // scores: S = Q @ K^T * scale
    for (int jt = 0; jt < 8; ++jt) {
        __syncthreads();
        #pragma unroll
        for (int l = 0; l < 4; ++l) {
            int idx = tid + l * 256;
            int r = idx >> 4, c4 = idx & 15;
            ushort4 kv = *reinterpret_cast<const ushort4*>(k + base + (size_t)(jt * 64 + r) * D_ + c4 * 4);
            KVs[c4 * 4 + 0][r] = us2f(kv.x); KVs[c4 * 4 + 1][r] = us2f(kv.y);
            KVs[c4 * 4 + 2][r] = us2f(kv.z); KVs[c4 * 4 + 3][r] = us2f(kv.w);
        }
        __syncthreads();
        float sa[4] = {0.f, 0.f, 0.f, 0.f};
        #pragma unroll
        for (int c = 0; c < 64; ++c) {
            float a = Qs[ty][c];
            float4 kb = *reinterpret_cast<const float4*>(&KVs[c][tx * 4]);
            sa[0] += a * kb.x; sa[1] += a * kb.y; sa[2] += a * kb.z; sa[3] += a * kb.w;
        }
        #pragma unroll
        for (int e = 0; e < 4; ++e) Sc[ty][jt * 64 + tx * 4 + e] = sa[e] * 0.125f;
    }
    __syncthreads();

    // softmax over 512 keys; wave w handles rows [w*4, w*4+4)
    {
        int lane = tid & 63;
        int w = tid >> 6;
        for (int r = w * 4; r < w * 4 + 4; ++r) {
            float vals[8]; float m = -1e30f;
            #pragma unroll
            for (int t = 0; t < 8; ++t) { vals[t] = Sc[r][lane + t * 64]; m = fmaxf(m, vals[t]); }
            #pragma unroll
            for (int off = 32; off > 0; off >>= 1) m = fmaxf(m, __shfl_xor(m, off, 64));
            float s = 0.f;
            #pragma unroll
            for (int t = 0; t < 8; ++t) { vals[t] = __expf(vals[t] - m); s += vals[t]; }
            #pragma unroll
            for (int off = 32; off > 0; off >>= 1) s += __shfl_xor(s, off, 64);
            float inv = 1.f / s;
            #pragma unroll
            for (int t = 0; t < 8; ++t) Sc[r][lane + t * 64] = vals[t] * inv;
        }
    }

    // ctx = P @ V
    float acc[4] = {0.f, 0.f, 0.f, 0.f};
    for (int jt = 0; jt < 8; ++jt) {
        __syncthreads();
        #pragma unroll
        for (int l = 0; l < 4; ++l) {
            int idx = tid + l * 256;
            int r = idx >> 4, c4 = idx & 15;
            ushort4 vv = *reinterpret_cast<const ushort4*>(v + base + (size_t)(jt * 64 + r) * D_ + c4 * 4);
            KVs[r][c4 * 4 + 0] = us2f(vv.x); KVs[r][c4 * 4 + 1] = us2f(vv.y);
            KVs[r][c4 * 4 + 2] = us2f(vv.z); KVs[r][c4 * 4 + 3] = us2f(vv.w);
        }
        __syncthreads();
        #pragma unroll
        for (int jj = 0; jj < 64; ++jj) {
            float s = Sc[ty][jt * 64 + jj];
            float4 vb = *reinterpret_cast<const float4*>(&KVs[jj][tx * 4]);
            acc[0] += s * vb.x; acc[1] += s * vb.y; acc[2] += s * vb.z; acc[3] += s * vb.w;
        }
    }
    ushort4 o;
    o.x = f2us(acc[0]); o.y = f2us(acc[1]); o.z = f2us(acc[2]); o.w = f2us(acc[3]);
    *reinterpret_cast<ushort4*>(ctx + base + (size_t)(q0 + ty) * D_ + tx * 4) = o;
}

// ---------------------------------------------------------------------------
// Mean-pool stage 1: partial sums over 64-row chunks. grid (B, 8), block 256.
// ---------------------------------------------------------------------------
__global__ __launch_bounds__(256)
void pool_k(const bf16* __restrict__ x, float* __restrict__ partial)
{
    int b = blockIdx.x, ch = blockIdx.y, c = threadIdx.x;
    float s = 0.f;
    for (int n = ch * 64; n < ch * 64 + 64; ++n)
        s += bf2f(x[((size_t)b * N_ + n) * D_ + c]);
    partial[((size_t)b * 8 + ch) * D_ + c] = s;
}

// ---------------------------------------------------------------------------
// Mean-pool stage 2 + logits. grid B, block 256. out fp32 (B,2).
// ---------------------------------------------------------------------------
__global__ __launch_bounds__(256)
void logits_k(const float* __restrict__ partial, const float* __restrict__ Wc,
              const float* __restrict__ bc, float* __restrict__ out)
{
    __shared__ float pl[256];
    __shared__ float red[256];
    int b = blockIdx.x, c = threadIdx.x;
    float s = 0.f;
    for (int ch = 0; ch < 8; ++ch) s += partial[((size_t)b * 8 + ch) * D_ + c];
    pl[c] = s * (1.f / 512.f);
    __syncthreads();
    int o = c >> 7, cc = c & 127;
    red[c] = pl[cc] * Wc[o * 256 + cc] + pl[cc + 128] * Wc[o * 256 + cc + 128];
    __syncthreads();
    for (int st = 64; st > 0; st >>= 1) { if (cc < st) red[c] += red[c + st]; __syncthreads(); }
    if (cc == 0) out[b * 2 + o] = red[c] + bc[o];
}

// ---------------------------------------------------------------------------
extern "C" void kernel_launch(void* const* d_in, const int* in_sizes, int n_in,
                              void* d_out, int out_size, void* d_ws, size_t ws_size,
                              hipStream_t stream)
{
    const float* x   = (const float*)d_in[0];
    const float* y   = (const float*)d_in[1];
    // d_in[2] = z, unused by the reference
    const float* Wr  = (const float*)d_in[3];
    const float* br  = (const float*)d_in[4];
    const float* Wf  = (const float*)d_in[5];
    const float* bfv = (const float*)d_in[6];
    const float* gx  = (const float*)d_in[7];
    const float* bx  = (const float*)d_in[8];
    const float* gy  = (const float*)d_in[9];
    const float* by  = (const float*)d_in[10];
    const float* Wq  = (const float*)d_in[11];
    const float* bq  = (const float*)d_in[12];
    const float* Wk  = (const float*)d_in[13];
    const float* bk  = (const float*)d_in[14];
    const float* Wv  = (const float*)d_in[15];
    const float* bv  = (const float*)d_in[16];
    const float* Wo  = (const float*)d_in[17];
    const float* bo  = (const float*)d_in[18];
    const float* gm  = (const float*)d_in[19];
    const float* bm  = (const float*)d_in[20];
    const float* W1  = (const float*)d_in[21];
    const float* b1  = (const float*)d_in[22];
    const float* W2  = (const float*)d_in[23];
    const float* b2  = (const float*)d_in[24];
    const float* Wc  = (const float*)d_in[25];
    const float* bc  = (const float*)d_in[26];

    bf16* ws = (bf16*)d_ws;
    const size_t S = (size_t)B_ * N_ * D_;   // 8,388,608 elements per buffer
    bf16* bA = ws;                            // xp
    bf16* bB = ws + S;                        // yp -> x_mlp
    bf16* bC = ws + 2 * S;                    // q -> ctx (in-place)
    bf16* bD = ws + 3 * S;                    // k -> x_res
    bf16* bE = ws + 4 * S;                    // v -> mlp hidden
    float* part = (float*)(ws + 5 * S);       // 64*8*256 fp32 partials

    const int M = B_ * N_; // 32768 rows
    dim3 blk(256);
    dim3 gX(M / 64, D_ / 64);

    // xp = LN(x @ Wr.T + br + pe)
    gemm_k<0, 0><<<gX, blk, 0, stream>>>(x, Wr, br, nullptr, bA, M, D_, 769, 0);
    ln_k<<<M, blk, 0, stream>>>(bA, bA, gx, bx, 1);
    // yp = LN(y @ Wf.T + bf + pe)
    gemm_k<0, 0><<<gX, blk, 0, stream>>>(y, Wf, bfv, nullptr, bB, M, D_, 674, 0);
    ln_k<<<M, blk, 0, stream>>>(bB, bB, gy, by, 1);
    // q,k,v (K=256 -> vectorized loads)
    gemm_k<1, 1><<<gX, blk, 0, stream>>>(bA, Wq, bq, nullptr, bC, M, D_, D_, 0);
    gemm_k<1, 1><<<gX, blk, 0, stream>>>(bB, Wk, bk, nullptr, bD, M, D_, D_, 0);
    gemm_k<1, 1><<<gX, blk, 0, stream>>>(bB, Wv, bv, nullptr, bE, M, D_, D_, 0);
    // attention -> ctx (in-place over q)
    attn_k<<<B_ * H_ * (N_ / 16), blk, 0, stream>>>(bC, bD, bE, bC);
    // x_res = LN(xp + ctx @ Wo.T + bo)
    gemm_k<1, 1><<<gX, blk, 0, stream>>>(bC, Wo, bo, bA, bD, M, D_, D_, 0);
    ln_k<<<M, blk, 0, stream>>>(bD, bD, gm, bm, 0);
    // mlp
    gemm_k<1, 1><<<gX, blk, 0, stream>>>(bD, W1, b1, nullptr, bE, M, D_, D_, 1);
    gemm_k<1, 1><<<gX, blk, 0, stream>>>(bE, W2, b2, bD, bB, M, D_, D_, 0);
    // mean-pool + logits
    pool_k<<<dim3(B_, 8), blk, 0, stream>>>(bB, part);
    logits_k<<<B_, blk, 0, stream>>>(part, Wc, bc, (float*)d_out);
}

// Round 4
// 1688.199 us; speedup vs baseline: 1.1144x; 1.1144x over previous
//
#include <hip/hip_runtime.h>
#include <hip/hip_bf16.h>

// Problem constants
#define B_   64
#define N_   512
#define D_   256
#define H_   4
#define HD_  64

typedef __hip_bfloat16 bf16;
typedef __attribute__((ext_vector_type(8))) short short8;
typedef __attribute__((ext_vector_type(4))) float floatx4;

__device__ __forceinline__ float bf2f(bf16 v) { return __bfloat162float(v); }
__device__ __forceinline__ float us2f(unsigned short u) {
    union { unsigned int i; float f; } c; c.i = ((unsigned int)u) << 16; return c.f;
}
__device__ __forceinline__ unsigned short f2us(float f) {
    bf16 h = __float2bfloat16(f);
    union { bf16 h; unsigned short u; } c; c.h = h; return c.u;
}

// ---------------------------------------------------------------------------
// MFMA GEMM: C[m][n] = sum_k A[m][k]*W[n][k] (+bias) (relu) (+res). C bf16.
// A: fp32 (ABF16=0) or bf16 (ABF16=1). W fp32 (converted to bf16 in staging).
// Block tile 128x128, BK=32, 256 threads = 4 waves, each wave 64x64 via
// 4x4 grid of v_mfma_f32_16x16x32_bf16. LDS layout k-outer: As[g][m][8] so
// fragment reads are lane-contiguous ds_read_b128 (conflict-free) and
// A-frag for lane: row=lane&15(+16i), k=(lane>>4)*8+j  == As[quad][row][j].
// C/D layout: col=lane&15, row=(lane>>4)*4+reg (guide-verified m89/m91).
// WVEC=1 requires K%8==0 (16B-aligned float4 W loads). M%128==0, N%128==0.
// ---------------------------------------------------------------------------
template<int ABF16, int WVEC>
__global__ __launch_bounds__(256)
void gemm_mfma(const void* __restrict__ A_, const float* __restrict__ W,
               const float* __restrict__ bias, const bf16* __restrict__ res,
               bf16* __restrict__ C, int M, int N, int K, int relu)
{
    __shared__ bf16 As[4 * 128 * 8];   // [g][m][j]
    __shared__ bf16 Bs[4 * 128 * 8];   // [g][n][j]

    const int tid = threadIdx.x;
    const int m0 = blockIdx.x * 128;
    const int n0 = blockIdx.y * 128;
    const int lane = tid & 63;
    const int w = tid >> 6;
    const int wm = (w & 1) * 64, wn = (w >> 1) * 64;
    const int fr = lane & 15, quad = lane >> 4;

    floatx4 acc[4][4] = {};

    const int nk = (K + 31) / 32;
    for (int t = 0; t < nk; ++t) {
        const int k0 = t * 32;
        __syncthreads();
        #pragma unroll
        for (int r = 0; r < 2; ++r) {
            const int flat = r * 256 + tid;
            const int row = flat & 127;       // m (or n) within tile
            const int g   = flat >> 7;        // k-group 0..3
            // ---- A chunk: 8 bf16 at (m0+row, k0+g*8) -> As[g][row][*]
            if (ABF16) {
                const unsigned short* src =
                    (const unsigned short*)A_ + (size_t)(m0 + row) * K + k0 + g * 8;
                *(short8*)&As[(g * 128 + row) * 8] = *(const short8*)src;
            } else {
                const float* src = (const float*)A_ + (size_t)(m0 + row) * K;
                unsigned short tmp[8];
                #pragma unroll
                for (int j = 0; j < 8; ++j) {
                    int kk = k0 + g * 8 + j;
                    tmp[j] = f2us(kk < K ? src[kk] : 0.f);
                }
                *(short8*)&As[(g * 128 + row) * 8] = *(short8*)tmp;
            }
            // ---- W chunk: 8 fp32 -> bf16 at (n0+row, k0+g*8) -> Bs[g][row][*]
            {
                unsigned short tmp[8];
                if (WVEC) {
                    const float* srcw = W + (size_t)(n0 + row) * K + k0 + g * 8;
                    const float4 w0 = *(const float4*)(srcw);
                    const float4 w1 = *(const float4*)(srcw + 4);
                    tmp[0] = f2us(w0.x); tmp[1] = f2us(w0.y);
                    tmp[2] = f2us(w0.z); tmp[3] = f2us(w0.w);
                    tmp[4] = f2us(w1.x); tmp[5] = f2us(w1.y);
                    tmp[6] = f2us(w1.z); tmp[7] = f2us(w1.w);
                } else {
                    const float* srcw = W + (size_t)(n0 + row) * K;
                    #pragma unroll
                    for (int j = 0; j < 8; ++j) {
                        int kk = k0 + g * 8 + j;
                        tmp[j] = f2us(kk < K ? srcw[kk] : 0.f);
                    }
                }
                *(short8*)&Bs[(g * 128 + row) * 8] = *(short8*)tmp;
            }
        }
        __syncthreads();

        short8 a[4], b[4];
        #pragma unroll
        for (int i = 0; i < 4; ++i) {
            a[i] = *(const short8*)&As[(quad * 128 + wm + i * 16 + fr) * 8];
            b[i] = *(const short8*)&Bs[(quad * 128 + wn + i * 16 + fr) * 8];
        }
        #pragma unroll
        for (int im = 0; im < 4; ++im)
            #pragma unroll
            for (int in = 0; in < 4; ++in)
                acc[im][in] = __builtin_amdgcn_mfma_f32_16x16x32_bf16(
                    a[im], b[in], acc[im][in], 0, 0, 0);
    }

    // Epilogue
    #pragma unroll
    for (int im = 0; im < 4; ++im) {
        #pragma unroll
        for (int reg = 0; reg < 4; ++reg) {
            const int m = m0 + wm + im * 16 + quad * 4 + reg;
            #pragma unroll
            for (int in = 0; in < 4; ++in) {
                const int n = n0 + wn + in * 16 + fr;
                float v = acc[im][in][reg];
                if (bias) v += bias[n];
                if (relu) v = fmaxf(v, 0.f);
                if (res)  v += bf2f(res[(size_t)m * N + n]);
                C[(size_t)m * N + n] = __float2bfloat16(v);
            }
        }
    }
}

// ---------------------------------------------------------------------------
// LayerNorm over last dim (256), bf16 in/out (in-place safe), fp32 g/b,
// optional on-the-fly sinusoidal positional embedding.
// ---------------------------------------------------------------------------
__global__ __launch_bounds__(256)
void ln_k(const bf16* in, bf16* out,
          const float* __restrict__ g, const float* __restrict__ b, int use_pe)
{
    __shared__ float red[256];
    const int row = blockIdx.x;
    const int c = threadIdx.x;
    float v = bf2f(in[(size_t)row * D_ + c]);
    if (use_pe) {
        int n = row & (N_ - 1);
        int j = c & ~1;
        float freq = __expf(-(float)j * (9.210340371976184f / 256.0f)); // ln(10000)/d
        float ang = (float)n * freq;
        v += (c & 1) ? cosf(ang) : sinf(ang);
    }
    red[c] = v; __syncthreads();
    for (int s = 128; s > 0; s >>= 1) { if (c < s) red[c] += red[c + s]; __syncthreads(); }
    float mu = red[0] * (1.f / 256.f);
    __syncthreads();
    float d = v - mu;
    red[c] = d * d; __syncthreads();
    for (int s = 128; s > 0; s >>= 1) { if (c < s) red[c] += red[c + s]; __syncthreads(); }
    float var = red[0] * (1.f / 256.f);
    float rs = rsqrtf(var + 1e-5f);
    out[(size_t)row * D_ + c] = __float2bfloat16(d * rs * g[c] + b[c]);
}

// ---------------------------------------------------------------------------
// Cross-attention, non-causal. One block per (b, h, 16-query tile).
// q,k,v,ctx bf16 (B,N,D), head h at cols [h*64,h*64+64). ctx MAY alias q:
// each block writes exactly its own Q-tile region (staged in LDS first).
// ---------------------------------------------------------------------------
__global__ __launch_bounds__(256)
void attn_k(const bf16* q, const bf16* __restrict__ k,
            const bf16* __restrict__ v, bf16* ctx)
{
    constexpr int TQ = 16;
    __shared__ float Qs[TQ][HD_ + 4];      // [qrow][c]
    __shared__ float KVs[64][HD_ + 4];     // K phase: [c][j] transposed; V: [j][c]
    __shared__ float Sc[TQ][N_ + 4];       // scores/probs

    const int tid = threadIdx.x;
    const int qt = blockIdx.x & 31;
    const int h  = (blockIdx.x >> 5) & 3;
    const int b  = blockIdx.x >> 7;
    const int q0 = qt * TQ;
    const size_t base = ((size_t)b * N_) * D_ + h * HD_;

    {
        int r = tid >> 4, c4 = tid & 15;
        ushort4 qa = *reinterpret_cast<const ushort4*>(q + base + (size_t)(q0 + r) * D_ + c4 * 4);
        Qs[r][c4 * 4 + 0] = us2f(qa.x); Qs[r][c4 * 4 + 1] = us2f(qa.y);
        Qs[r][c4 * 4 + 2] = us2f(qa.z); Qs[r][c4 * 4 + 3] = us2f(qa.w);
    }
    const int tx = tid & 15, ty = tid >> 4;

    // scores: S = Q @ K^T * scale
    for (int jt = 0; jt < 8; ++jt) {
        __syncthreads();
        #pragma unroll
        for (int l = 0; l < 4; ++l) {
            int idx = tid + l * 256;
            int r = idx >> 4, c4 = idx & 15;
            ushort4 kv = *reinterpret_cast<const ushort4*>(k + base + (size_t)(jt * 64 + r) * D_ + c4 * 4);
            KVs[c4 * 4 + 0][r] = us2f(kv.x); KVs[c4 * 4 + 1][r] = us2f(kv.y);
            KVs[c4 * 4 + 2][r] = us2f(kv.z); KVs[c4 * 4 + 3][r] = us2f(kv.w);
        }
        __syncthreads();
        float sa[4] = {0.f, 0.f, 0.f, 0.f};
        #pragma unroll
        for (int c = 0; c < 64; ++c) {
            float a = Qs[ty][c];
            float4 kb = *reinterpret_cast<const float4*>(&KVs[c][tx * 4]);
            sa[0] += a * kb.x; sa[1] += a * kb.y; sa[2] += a * kb.z; sa[3] += a * kb.w;
        }
        #pragma unroll
        for (int e = 0; e < 4; ++e) Sc[ty][jt * 64 + tx * 4 + e] = sa[e] * 0.125f;
    }
    __syncthreads();

    // softmax over 512 keys; wave w handles rows [w*4, w*4+4)
    {
        int lane = tid & 63;
        int w = tid >> 6;
        for (int r = w * 4; r < w * 4 + 4; ++r) {
            float vals[8]; float m = -1e30f;
            #pragma unroll
            for (int t = 0; t < 8; ++t) { vals[t] = Sc[r][lane + t * 64]; m = fmaxf(m, vals[t]); }
            #pragma unroll
            for (int off = 32; off > 0; off >>= 1) m = fmaxf(m, __shfl_xor(m, off, 64));
            float s = 0.f;
            #pragma unroll
            for (int t = 0; t < 8; ++t) { vals[t] = __expf(vals[t] - m); s += vals[t]; }
            #pragma unroll
            for (int off = 32; off > 0; off >>= 1) s += __shfl_xor(s, off, 64);
            float inv = 1.f / s;
            #pragma unroll
            for (int t = 0; t < 8; ++t) Sc[r][lane + t * 64] = vals[t] * inv;
        }
    }

    // ctx = P @ V
    float acc[4] = {0.f, 0.f, 0.f, 0.f};
    for (int jt = 0; jt < 8; ++jt) {
        __syncthreads();
        #pragma unroll
        for (int l = 0; l < 4; ++l) {
            int idx = tid + l * 256;
            int r = idx >> 4, c4 = idx & 15;
            ushort4 vv = *reinterpret_cast<const ushort4*>(v + base + (size_t)(jt * 64 + r) * D_ + c4 * 4);
            KVs[r][c4 * 4 + 0] = us2f(vv.x); KVs[r][c4 * 4 + 1] = us2f(vv.y);
            KVs[r][c4 * 4 + 2] = us2f(vv.z); KVs[r][c4 * 4 + 3] = us2f(vv.w);
        }
        __syncthreads();
        #pragma unroll
        for (int jj = 0; jj < 64; ++jj) {
            float s = Sc[ty][jt * 64 + jj];
            float4 vb = *reinterpret_cast<const float4*>(&KVs[jj][tx * 4]);
            acc[0] += s * vb.x; acc[1] += s * vb.y; acc[2] += s * vb.z; acc[3] += s * vb.w;
        }
    }
    ushort4 o;
    o.x = f2us(acc[0]); o.y = f2us(acc[1]); o.z = f2us(acc[2]); o.w = f2us(acc[3]);
    *reinterpret_cast<ushort4*>(ctx + base + (size_t)(q0 + ty) * D_ + tx * 4) = o;
}

// ---------------------------------------------------------------------------
// Mean-pool stage 1: partial sums over 64-row chunks. grid (B, 8), block 256.
// ---------------------------------------------------------------------------
__global__ __launch_bounds__(256)
void pool_k(const bf16* __restrict__ x, float* __restrict__ partial)
{
    int b = blockIdx.x, ch = blockIdx.y, c = threadIdx.x;
    float s = 0.f;
    for (int n = ch * 64; n < ch * 64 + 64; ++n)
        s += bf2f(x[((size_t)b * N_ + n) * D_ + c]);
    partial[((size_t)b * 8 + ch) * D_ + c] = s;
}

// ---------------------------------------------------------------------------
// Mean-pool stage 2 + logits. grid B, block 256. out fp32 (B,2).
// ---------------------------------------------------------------------------
__global__ __launch_bounds__(256)
void logits_k(const float* __restrict__ partial, const float* __restrict__ Wc,
              const float* __restrict__ bc, float* __restrict__ out)
{
    __shared__ float pl[256];
    __shared__ float red[256];
    int b = blockIdx.x, c = threadIdx.x;
    float s = 0.f;
    for (int ch = 0; ch < 8; ++ch) s += partial[((size_t)b * 8 + ch) * D_ + c];
    pl[c] = s * (1.f / 512.f);
    __syncthreads();
    int o = c >> 7, cc = c & 127;
    red[c] = pl[cc] * Wc[o * 256 + cc] + pl[cc + 128] * Wc[o * 256 + cc + 128];
    __syncthreads();
    for (int st = 64; st > 0; st >>= 1) { if (cc < st) red[c] += red[c + st]; __syncthreads(); }
    if (cc == 0) out[b * 2 + o] = red[c] + bc[o];
}

// ---------------------------------------------------------------------------
extern "C" void kernel_launch(void* const* d_in, const int* in_sizes, int n_in,
                              void* d_out, int out_size, void* d_ws, size_t ws_size,
                              hipStream_t stream)
{
    const float* x   = (const float*)d_in[0];
    const float* y   = (const float*)d_in[1];
    // d_in[2] = z, unused by the reference
    const float* Wr  = (const float*)d_in[3];
    const float* br  = (const float*)d_in[4];
    const float* Wf  = (const float*)d_in[5];
    const float* bfv = (const float*)d_in[6];
    const float* gx  = (const float*)d_in[7];
    const float* bx  = (const float*)d_in[8];
    const float* gy  = (const float*)d_in[9];
    const float* by  = (const float*)d_in[10];
    const float* Wq  = (const float*)d_in[11];
    const float* bq  = (const float*)d_in[12];
    const float* Wk  = (const float*)d_in[13];
    const float* bk  = (const float*)d_in[14];
    const float* Wv  = (const float*)d_in[15];
    const float* bv  = (const float*)d_in[16];
    const float* Wo  = (const float*)d_in[17];
    const float* bo  = (const float*)d_in[18];
    const float* gm  = (const float*)d_in[19];
    const float* bm  = (const float*)d_in[20];
    const float* W1  = (const float*)d_in[21];
    const float* b1  = (const float*)d_in[22];
    const float* W2  = (const float*)d_in[23];
    const float* b2  = (const float*)d_in[24];
    const float* Wc  = (const float*)d_in[25];
    const float* bc  = (const float*)d_in[26];

    bf16* ws = (bf16*)d_ws;
    const size_t S = (size_t)B_ * N_ * D_;   // 8,388,608 elements per buffer
    bf16* bA = ws;                            // xp
    bf16* bB = ws + S;                        // yp -> x_mlp
    bf16* bC = ws + 2 * S;                    // q -> ctx (in-place)
    bf16* bD = ws + 3 * S;                    // k -> x_res
    bf16* bE = ws + 4 * S;                    // v -> mlp hidden
    float* part = (float*)(ws + 5 * S);       // 64*8*256 fp32 partials

    const int M = B_ * N_; // 32768 rows
    dim3 blk(256);
    dim3 gG(M / 128, D_ / 128);               // 256 x 2 blocks

    // xp = LN(x @ Wr.T + br + pe)
    gemm_mfma<0, 0><<<gG, blk, 0, stream>>>(x, Wr, br, nullptr, bA, M, D_, 769, 0);
    ln_k<<<M, blk, 0, stream>>>(bA, bA, gx, bx, 1);
    // yp = LN(y @ Wf.T + bf + pe)
    gemm_mfma<0, 0><<<gG, blk, 0, stream>>>(y, Wf, bfv, nullptr, bB, M, D_, 674, 0);
    ln_k<<<M, blk, 0, stream>>>(bB, bB, gy, by, 1);
    // q,k,v
    gemm_mfma<1, 1><<<gG, blk, 0, stream>>>(bA, Wq, bq, nullptr, bC, M, D_, D_, 0);
    gemm_mfma<1, 1><<<gG, blk, 0, stream>>>(bB, Wk, bk, nullptr, bD, M, D_, D_, 0);
    gemm_mfma<1, 1><<<gG, blk, 0, stream>>>(bB, Wv, bv, nullptr, bE, M, D_, D_, 0);
    // attention -> ctx (in-place over q)
    attn_k<<<B_ * H_ * (N_ / 16), blk, 0, stream>>>(bC, bD, bE, bC);
    // x_res = LN(xp + ctx @ Wo.T + bo)
    gemm_mfma<1, 1><<<gG, blk, 0, stream>>>(bC, Wo, bo, bA, bD, M, D_, D_, 0);
    ln_k<<<M, blk, 0, stream>>>(bD, bD, gm, bm, 0);
    // mlp
    gemm_mfma<1, 1><<<gG, blk, 0, stream>>>(bD, W1, b1, nullptr, bE, M, D_, D_, 1);
    gemm_mfma<1, 1><<<gG, blk, 0, stream>>>(bE, W2, b2, bD, bB, M, D_, D_, 0);
    // mean-pool + logits
    pool_k<<<dim3(B_, 8), blk, 0, stream>>>(bB, part);
    logits_k<<<B_, blk, 0, stream>>>(part, Wc, bc, (float*)d_out);
}

// Round 5
// 1175.717 us; speedup vs baseline: 1.6002x; 1.4359x over previous
//
#include <hip/hip_runtime.h>
#include <hip/hip_bf16.h>

// Problem constants
#define B_   64
#define N_   512
#define D_   256
#define H_   4
#define HD_  64

typedef __hip_bfloat16 bf16;
typedef __attribute__((ext_vector_type(8))) short short8;
typedef __attribute__((ext_vector_type(4))) float floatx4;

__device__ __forceinline__ float bf2f(bf16 v) { return __bfloat162float(v); }
__device__ __forceinline__ float us2f(unsigned short u) {
    union { unsigned int i; float f; } c; c.i = ((unsigned int)u) << 16; return c.f;
}
__device__ __forceinline__ unsigned short f2us(float f) {
    bf16 h = __float2bfloat16(f);
    union { bf16 h; unsigned short u; } c; c.h = h; return c.u;
}

// ---------------------------------------------------------------------------
// MFMA GEMM (unchanged from round 4): C = A*W^T (+bias)(relu)(+res), C bf16.
// ---------------------------------------------------------------------------
template<int ABF16, int WVEC>
__global__ __launch_bounds__(256)
void gemm_mfma(const void* __restrict__ A_, const float* __restrict__ W,
               const float* __restrict__ bias, const bf16* __restrict__ res,
               bf16* __restrict__ C, int M, int N, int K, int relu)
{
    __shared__ bf16 As[4 * 128 * 8];   // [g][m][j]
    __shared__ bf16 Bs[4 * 128 * 8];   // [g][n][j]

    const int tid = threadIdx.x;
    const int m0 = blockIdx.x * 128;
    const int n0 = blockIdx.y * 128;
    const int lane = tid & 63;
    const int w = tid >> 6;
    const int wm = (w & 1) * 64, wn = (w >> 1) * 64;
    const int fr = lane & 15, quad = lane >> 4;

    floatx4 acc[4][4] = {};

    const int nk = (K + 31) / 32;
    for (int t = 0; t < nk; ++t) {
        const int k0 = t * 32;
        __syncthreads();
        #pragma unroll
        for (int r = 0; r < 2; ++r) {
            const int flat = r * 256 + tid;
            const int row = flat & 127;
            const int g   = flat >> 7;
            if (ABF16) {
                const unsigned short* src =
                    (const unsigned short*)A_ + (size_t)(m0 + row) * K + k0 + g * 8;
                *(short8*)&As[(g * 128 + row) * 8] = *(const short8*)src;
            } else {
                const float* src = (const float*)A_ + (size_t)(m0 + row) * K;
                unsigned short tmp[8];
                #pragma unroll
                for (int j = 0; j < 8; ++j) {
                    int kk = k0 + g * 8 + j;
                    tmp[j] = f2us(kk < K ? src[kk] : 0.f);
                }
                *(short8*)&As[(g * 128 + row) * 8] = *(short8*)tmp;
            }
            {
                unsigned short tmp[8];
                if (WVEC) {
                    const float* srcw = W + (size_t)(n0 + row) * K + k0 + g * 8;
                    const float4 w0 = *(const float4*)(srcw);
                    const float4 w1 = *(const float4*)(srcw + 4);
                    tmp[0] = f2us(w0.x); tmp[1] = f2us(w0.y);
                    tmp[2] = f2us(w0.z); tmp[3] = f2us(w0.w);
                    tmp[4] = f2us(w1.x); tmp[5] = f2us(w1.y);
                    tmp[6] = f2us(w1.z); tmp[7] = f2us(w1.w);
                } else {
                    const float* srcw = W + (size_t)(n0 + row) * K;
                    #pragma unroll
                    for (int j = 0; j < 8; ++j) {
                        int kk = k0 + g * 8 + j;
                        tmp[j] = f2us(kk < K ? srcw[kk] : 0.f);
                    }
                }
                *(short8*)&Bs[(g * 128 + row) * 8] = *(short8*)tmp;
            }
        }
        __syncthreads();

        short8 a[4], b[4];
        #pragma unroll
        for (int i = 0; i < 4; ++i) {
            a[i] = *(const short8*)&As[(quad * 128 + wm + i * 16 + fr) * 8];
            b[i] = *(const short8*)&Bs[(quad * 128 + wn + i * 16 + fr) * 8];
        }
        #pragma unroll
        for (int im = 0; im < 4; ++im)
            #pragma unroll
            for (int in = 0; in < 4; ++in)
                acc[im][in] = __builtin_amdgcn_mfma_f32_16x16x32_bf16(
                    a[im], b[in], acc[im][in], 0, 0, 0);
    }

    #pragma unroll
    for (int im = 0; im < 4; ++im) {
        #pragma unroll
        for (int reg = 0; reg < 4; ++reg) {
            const int m = m0 + wm + im * 16 + quad * 4 + reg;
            #pragma unroll
            for (int in = 0; in < 4; ++in) {
                const int n = n0 + wn + in * 16 + fr;
                float v = acc[im][in][reg];
                if (bias) v += bias[n];
                if (relu) v = fmaxf(v, 0.f);
                if (res)  v += bf2f(res[(size_t)m * N + n]);
                C[(size_t)m * N + n] = __float2bfloat16(v);
            }
        }
    }
}

// ---------------------------------------------------------------------------
// LayerNorm over last dim (256), bf16 in/out, fp32 g/b, optional PE.
// ---------------------------------------------------------------------------
__global__ __launch_bounds__(256)
void ln_k(const bf16* in, bf16* out,
          const float* __restrict__ g, const float* __restrict__ b, int use_pe)
{
    __shared__ float red[256];
    const int row = blockIdx.x;
    const int c = threadIdx.x;
    float v = bf2f(in[(size_t)row * D_ + c]);
    if (use_pe) {
        int n = row & (N_ - 1);
        int j = c & ~1;
        float freq = __expf(-(float)j * (9.210340371976184f / 256.0f));
        float ang = (float)n * freq;
        v += (c & 1) ? cosf(ang) : sinf(ang);
    }
    red[c] = v; __syncthreads();
    for (int s = 128; s > 0; s >>= 1) { if (c < s) red[c] += red[c + s]; __syncthreads(); }
    float mu = red[0] * (1.f / 256.f);
    __syncthreads();
    float d = v - mu;
    red[c] = d * d; __syncthreads();
    for (int s = 128; s > 0; s >>= 1) { if (c < s) red[c] += red[c + s]; __syncthreads(); }
    float var = red[0] * (1.f / 256.f);
    float rs = rsqrtf(var + 1e-5f);
    out[(size_t)row * D_ + c] = __float2bfloat16(d * rs * g[c] + b[c]);
}

// ---------------------------------------------------------------------------
// MFMA flash-style cross-attention. One block per (b, h, 64-query tile);
// grid = B*H*8 = 2048, 256 threads = 4 waves, wave w owns q-rows w*16..+15.
// Online softmax over 8 key-tiles of 64. ctx may alias q (block reads its own
// q-rows into LDS before writing the same region).
// Layouts (16x16x32 bf16 MFMA, guide-verified):
//   A-frag: row=lane&15, k=(lane>>4)*8+j ; C/D: col=lane&15, row=(lane>>4)*4+reg
//   Qs/Ks: [g][row][8] k-group major (conflict-free b128 frag reads)
//   Vs:    [gkey][d][8] = V transposed during staging (scalar b16 writes)
//   Ps:    per-wave [16][72] bf16 (stride 72 -> 144B rows: aligned, 2-way free)
// ---------------------------------------------------------------------------
__global__ __launch_bounds__(256)
void attn_k(const bf16* q, const bf16* __restrict__ k,
            const bf16* __restrict__ v, bf16* ctx)
{
    __shared__ bf16 Qs[8 * 64 * 8];
    __shared__ bf16 Ks[8 * 64 * 8];
    __shared__ bf16 Vs[8 * 64 * 8];
    __shared__ bf16 Ps[4 * 16 * 72];

    const int tid = threadIdx.x;
    const int qt = blockIdx.x & 7;
    const int h  = (blockIdx.x >> 3) & 3;
    const int b  = blockIdx.x >> 5;
    const int q0 = qt * 64;
    const size_t base = ((size_t)b * N_) * D_ + h * HD_;

    const int lane = tid & 63;
    const int w = tid >> 6;
    const int fr = lane & 15, quad = lane >> 4;

    // ---- stage Q tile 64x64: thread -> row=t>>2, d0=(t&3)*16 (2 short8)
    {
        const int row = tid >> 2, c = tid & 3;
        const unsigned short* src = (const unsigned short*)q + base + (size_t)(q0 + row) * D_ + c * 16;
        *(short8*)&Qs[((c * 2 + 0) * 64 + row) * 8] = *(const short8*)(src);
        *(short8*)&Qs[((c * 2 + 1) * 64 + row) * 8] = *(const short8*)(src + 8);
    }
    __syncthreads();

    // Q fragments (held in regs for whole kernel)
    short8 aq[2];
    #pragma unroll
    for (int ks = 0; ks < 2; ++ks)
        aq[ks] = *(const short8*)&Qs[((ks * 4 + quad) * 64 + w * 16 + fr) * 8];

    floatx4 O[4] = {};               // ctx accumulator, C-layout, d-tiles in
    float mrun[4], lrun[4];
    #pragma unroll
    for (int r = 0; r < 4; ++r) { mrun[r] = -1e30f; lrun[r] = 0.f; }

    for (int kt = 0; kt < 8; ++kt) {
        __syncthreads();   // protect Ks/Vs against previous iteration's reads
        // ---- stage K tile (row-copy) and V tile (transposed)
        {
            const int row = tid >> 2, c = tid & 3;
            const unsigned short* srck = (const unsigned short*)k + base + (size_t)(kt * 64 + row) * D_ + c * 16;
            *(short8*)&Ks[((c * 2 + 0) * 64 + row) * 8] = *(const short8*)(srck);
            *(short8*)&Ks[((c * 2 + 1) * 64 + row) * 8] = *(const short8*)(srck + 8);

            const int key = row, gk = key >> 3, jk = key & 7;
            const unsigned short* srcv = (const unsigned short*)v + base + (size_t)(kt * 64 + key) * D_ + c * 16;
            #pragma unroll
            for (int u = 0; u < 4; ++u) {
                ushort4 vv = *(const ushort4*)(srcv + u * 4);
                const int d0 = c * 16 + u * 4;
                Vs[(gk * 64 + d0 + 0) * 8 + jk] = *(bf16*)&vv.x;
                Vs[(gk * 64 + d0 + 1) * 8 + jk] = *(bf16*)&vv.y;
                Vs[(gk * 64 + d0 + 2) * 8 + jk] = *(bf16*)&vv.z;
                Vs[(gk * 64 + d0 + 3) * 8 + jk] = *(bf16*)&vv.w;
            }
        }
        __syncthreads();

        // ---- S = Q @ K^T * scale   (wave tile 16x64: 4 n-tiles)
        floatx4 S[4] = {};
        #pragma unroll
        for (int in = 0; in < 4; ++in) {
            #pragma unroll
            for (int ks = 0; ks < 2; ++ks) {
                short8 bk = *(const short8*)&Ks[((ks * 4 + quad) * 64 + in * 16 + fr) * 8];
                S[in] = __builtin_amdgcn_mfma_f32_16x16x32_bf16(aq[ks], bk, S[in], 0, 0, 0);
            }
        }
        #pragma unroll
        for (int in = 0; in < 4; ++in) S[in] *= 0.125f;

        // ---- online softmax update (rows = quad*4+reg)
        #pragma unroll
        for (int r = 0; r < 4; ++r) {
            float mloc = fmaxf(fmaxf(S[0][r], S[1][r]), fmaxf(S[2][r], S[3][r]));
            #pragma unroll
            for (int off = 1; off < 16; off <<= 1) mloc = fmaxf(mloc, __shfl_xor(mloc, off, 64));
            float mnew = fmaxf(mrun[r], mloc);
            float alpha = __expf(mrun[r] - mnew);
            float rs = 0.f;
            #pragma unroll
            for (int in = 0; in < 4; ++in) {
                float p = __expf(S[in][r] - mnew);
                S[in][r] = p;
                rs += p;
            }
            #pragma unroll
            for (int off = 1; off < 16; off <<= 1) rs += __shfl_xor(rs, off, 64);
            lrun[r] = lrun[r] * alpha + rs;
            mrun[r] = mnew;
            #pragma unroll
            for (int in = 0; in < 4; ++in) O[in][r] *= alpha;
        }

        // ---- P (C-layout) -> per-wave LDS -> A-frags
        #pragma unroll
        for (int in = 0; in < 4; ++in)
            #pragma unroll
            for (int r = 0; r < 4; ++r)
                Ps[(w * 16 + quad * 4 + r) * 72 + in * 16 + fr] = __float2bfloat16(S[in][r]);
        // wave-local region: compiler orders ds_write->ds_read via lgkmcnt
        short8 pa[2];
        #pragma unroll
        for (int ks = 0; ks < 2; ++ks)
            pa[ks] = *(const short8*)&Ps[(w * 16 + fr) * 72 + ks * 32 + quad * 8];

        // ---- O += P @ V
        #pragma unroll
        for (int in = 0; in < 4; ++in) {
            #pragma unroll
            for (int ks = 0; ks < 2; ++ks) {
                short8 bv = *(const short8*)&Vs[((ks * 4 + quad) * 64 + in * 16 + fr) * 8];
                O[in] = __builtin_amdgcn_mfma_f32_16x16x32_bf16(pa[ks], bv, O[in], 0, 0, 0);
            }
        }
    }

    // ---- normalize and write ctx (C-layout scatter; block-private region)
    #pragma unroll
    for (int r = 0; r < 4; ++r) {
        const float inv = 1.f / lrun[r];
        const int row = q0 + w * 16 + quad * 4 + r;
        #pragma unroll
        for (int in = 0; in < 4; ++in)
            ctx[base + (size_t)row * D_ + in * 16 + fr] = __float2bfloat16(O[in][r] * inv);
    }
}

// ---------------------------------------------------------------------------
// Mean-pool stage 1: partial sums over 64-row chunks. grid (B, 8), block 256.
// ---------------------------------------------------------------------------
__global__ __launch_bounds__(256)
void pool_k(const bf16* __restrict__ x, float* __restrict__ partial)
{
    int b = blockIdx.x, ch = blockIdx.y, c = threadIdx.x;
    float s = 0.f;
    for (int n = ch * 64; n < ch * 64 + 64; ++n)
        s += bf2f(x[((size_t)b * N_ + n) * D_ + c]);
    partial[((size_t)b * 8 + ch) * D_ + c] = s;
}

// ---------------------------------------------------------------------------
// Mean-pool stage 2 + logits. grid B, block 256. out fp32 (B,2).
// ---------------------------------------------------------------------------
__global__ __launch_bounds__(256)
void logits_k(const float* __restrict__ partial, const float* __restrict__ Wc,
              const float* __restrict__ bc, float* __restrict__ out)
{
    __shared__ float pl[256];
    __shared__ float red[256];
    int b = blockIdx.x, c = threadIdx.x;
    float s = 0.f;
    for (int ch = 0; ch < 8; ++ch) s += partial[((size_t)b * 8 + ch) * D_ + c];
    pl[c] = s * (1.f / 512.f);
    __syncthreads();
    int o = c >> 7, cc = c & 127;
    red[c] = pl[cc] * Wc[o * 256 + cc] + pl[cc + 128] * Wc[o * 256 + cc + 128];
    __syncthreads();
    for (int st = 64; st > 0; st >>= 1) { if (cc < st) red[c] += red[c + st]; __syncthreads(); }
    if (cc == 0) out[b * 2 + o] = red[c] + bc[o];
}

// ---------------------------------------------------------------------------
extern "C" void kernel_launch(void* const* d_in, const int* in_sizes, int n_in,
                              void* d_out, int out_size, void* d_ws, size_t ws_size,
                              hipStream_t stream)
{
    const float* x   = (const float*)d_in[0];
    const float* y   = (const float*)d_in[1];
    // d_in[2] = z, unused by the reference
    const float* Wr  = (const float*)d_in[3];
    const float* br  = (const float*)d_in[4];
    const float* Wf  = (const float*)d_in[5];
    const float* bfv = (const float*)d_in[6];
    const float* gx  = (const float*)d_in[7];
    const float* bx  = (const float*)d_in[8];
    const float* gy  = (const float*)d_in[9];
    const float* by  = (const float*)d_in[10];
    const float* Wq  = (const float*)d_in[11];
    const float* bq  = (const float*)d_in[12];
    const float* Wk  = (const float*)d_in[13];
    const float* bk  = (const float*)d_in[14];
    const float* Wv  = (const float*)d_in[15];
    const float* bv  = (const float*)d_in[16];
    const float* Wo  = (const float*)d_in[17];
    const float* bo  = (const float*)d_in[18];
    const float* gm  = (const float*)d_in[19];
    const float* bm  = (const float*)d_in[20];
    const float* W1  = (const float*)d_in[21];
    const float* b1  = (const float*)d_in[22];
    const float* W2  = (const float*)d_in[23];
    const float* b2  = (const float*)d_in[24];
    const float* Wc  = (const float*)d_in[25];
    const float* bc  = (const float*)d_in[26];

    bf16* ws = (bf16*)d_ws;
    const size_t S = (size_t)B_ * N_ * D_;   // 8,388,608 elements per buffer
    bf16* bA = ws;                            // xp
    bf16* bB = ws + S;                        // yp -> x_mlp
    bf16* bC = ws + 2 * S;                    // q -> ctx (in-place)
    bf16* bD = ws + 3 * S;                    // k -> x_res
    bf16* bE = ws + 4 * S;                    // v -> mlp hidden
    float* part = (float*)(ws + 5 * S);       // 64*8*256 fp32 partials

    const int M = B_ * N_; // 32768 rows
    dim3 blk(256);
    dim3 gG(M / 128, D_ / 128);               // 256 x 2 blocks

    // xp = LN(x @ Wr.T + br + pe)
    gemm_mfma<0, 0><<<gG, blk, 0, stream>>>(x, Wr, br, nullptr, bA, M, D_, 769, 0);
    ln_k<<<M, blk, 0, stream>>>(bA, bA, gx, bx, 1);
    // yp = LN(y @ Wf.T + bf + pe)
    gemm_mfma<0, 0><<<gG, blk, 0, stream>>>(y, Wf, bfv, nullptr, bB, M, D_, 674, 0);
    ln_k<<<M, blk, 0, stream>>>(bB, bB, gy, by, 1);
    // q,k,v
    gemm_mfma<1, 1><<<gG, blk, 0, stream>>>(bA, Wq, bq, nullptr, bC, M, D_, D_, 0);
    gemm_mfma<1, 1><<<gG, blk, 0, stream>>>(bB, Wk, bk, nullptr, bD, M, D_, D_, 0);
    gemm_mfma<1, 1><<<gG, blk, 0, stream>>>(bB, Wv, bv, nullptr, bE, M, D_, D_, 0);
    // attention -> ctx (in-place over q)
    attn_k<<<B_ * H_ * 8, blk, 0, stream>>>(bC, bD, bE, bC);
    // x_res = LN(xp + ctx @ Wo.T + bo)
    gemm_mfma<1, 1><<<gG, blk, 0, stream>>>(bC, Wo, bo, bA, bD, M, D_, D_, 0);
    ln_k<<<M, blk, 0, stream>>>(bD, bD, gm, bm, 0);
    // mlp
    gemm_mfma<1, 1><<<gG, blk, 0, stream>>>(bD, W1, b1, nullptr, bE, M, D_, D_, 1);
    gemm_mfma<1, 1><<<gG, blk, 0, stream>>>(bE, W2, b2, bD, bB, M, D_, D_, 0);
    // mean-pool + logits
    pool_k<<<dim3(B_, 8), blk, 0, stream>>>(bB, part);
    logits_k<<<B_, blk, 0, stream>>>(part, Wc, bc, (float*)d_out);
}

// Round 6
// 1064.455 us; speedup vs baseline: 1.7674x; 1.1045x over previous
//
#include <hip/hip_runtime.h>
#include <hip/hip_bf16.h>

// Problem constants
#define B_   64
#define N_   512
#define D_   256
#define H_   4
#define HD_  64

typedef __hip_bfloat16 bf16;
typedef __attribute__((ext_vector_type(8))) short short8;
typedef __attribute__((ext_vector_type(4))) float floatx4;

__device__ __forceinline__ float bf2f(bf16 v) { return __bfloat162float(v); }
__device__ __forceinline__ unsigned short f2us(float f) {
    bf16 h = __float2bfloat16(f);
    union { bf16 h; unsigned short u; } c; c.h = h; return c.u;
}

// ---------------------------------------------------------------------------
// Weight pre-convert: fp32 -> bf16, zero-padded rows Kreal -> Kp (K%32==0).
// One dispatch handles all 8 weight matrices (blockIdx.y = segment).
// dst layout: Wr[256*800] Wf[256*704] Wq Wk Wv Wo W1 W2 [256*256 each].
// ---------------------------------------------------------------------------
__global__ __launch_bounds__(256)
void convw_k(const float* __restrict__ Wr, const float* __restrict__ Wf,
             const float* __restrict__ Wq, const float* __restrict__ Wk,
             const float* __restrict__ Wv, const float* __restrict__ Wo,
             const float* __restrict__ W1, const float* __restrict__ W2,
             bf16* __restrict__ dst)
{
    const int seg = blockIdx.y;
    const float* src; int Kreal, Kp; size_t off;
    switch (seg) {
        case 0: src = Wr; Kreal = 769; Kp = 800; off = 0; break;
        case 1: src = Wf; Kreal = 674; Kp = 704; off = 256 * 800; break;
        default:
            src = (seg == 2) ? Wq : (seg == 3) ? Wk : (seg == 4) ? Wv
                : (seg == 5) ? Wo : (seg == 6) ? W1 : W2;
            Kreal = 256; Kp = 256;
            off = 256 * 800 + 256 * 704 + (size_t)(seg - 2) * 256 * 256;
            break;
    }
    const int idx = blockIdx.x * 256 + threadIdx.x;   // unit = 8 outputs
    if (idx >= 256 * Kp / 8) return;
    const int rowk = idx * 8;
    const int n = rowk / Kp, k0 = rowk % Kp;
    unsigned short tmp[8];
    #pragma unroll
    for (int j = 0; j < 8; ++j) {
        int kk = k0 + j;
        tmp[j] = f2us(kk < Kreal ? src[(size_t)n * Kreal + kk] : 0.f);
    }
    *(short8*)&dst[off + (size_t)rowk] = *(short8*)tmp;
}

// ---------------------------------------------------------------------------
// MFMA GEMM, 64x64 tile (2048 blocks for M=32768,N=256 -> ~8 blocks/CU).
// C[m][n] = sum_k A[m][k]*W[n][k] (+bias)(relu)(+res). C bf16, acc fp32.
// A: fp32 (AF32=1, stride lda, guarded to Kreal) or bf16 (stride lda, K%32==0,
// 16B-aligned). W: pre-converted bf16, stride ldw=Kp, zero-padded.
// 256 thr = 4 waves; wave quadrant 32x32 = 2x2 of mfma_f32_16x16x32_bf16.
// LDS k-group-major [g][row][8]: staging short8 ds_write_b128 + frag
// ds_read_b128, conflict-free (same pattern as verified 128-tile kernel).
// ---------------------------------------------------------------------------
template<int AF32>
__global__ __launch_bounds__(256)
void gemm64(const void* __restrict__ A_, int lda,
            const bf16* __restrict__ W, int ldw,
            const float* __restrict__ bias, const bf16* __restrict__ res,
            bf16* __restrict__ C, int M, int N, int Kp, int Kreal, int relu)
{
    __shared__ bf16 As[4 * 64 * 8];
    __shared__ bf16 Bs[4 * 64 * 8];

    const int tid = threadIdx.x;
    const int m0 = blockIdx.x * 64;
    const int n0 = blockIdx.y * 64;
    const int lane = tid & 63;
    const int w = tid >> 6;
    const int wm = (w & 1) * 32, wn = (w >> 1) * 32;
    const int fr = lane & 15, quad = lane >> 4;
    const int srow = tid & 63, sg = tid >> 6;   // staging row / k-group

    floatx4 acc[2][2] = {};

    for (int k0 = 0; k0 < Kp; k0 += 32) {
        __syncthreads();
        // ---- A chunk: 8 elems at (m0+srow, k0+sg*8) -> As[sg][srow][*]
        if (AF32) {
            const float* src = (const float*)A_ + (size_t)(m0 + srow) * lda;
            unsigned short tmp[8];
            #pragma unroll
            for (int j = 0; j < 8; ++j) {
                int kk = k0 + sg * 8 + j;
                tmp[j] = f2us(kk < Kreal ? src[kk] : 0.f);
            }
            *(short8*)&As[(sg * 64 + srow) * 8] = *(short8*)tmp;
        } else {
            const unsigned short* src =
                (const unsigned short*)A_ + (size_t)(m0 + srow) * lda + k0 + sg * 8;
            *(short8*)&As[(sg * 64 + srow) * 8] = *(const short8*)src;
        }
        // ---- W chunk (pre-converted bf16, padded)
        {
            const unsigned short* srcw =
                (const unsigned short*)W + (size_t)(n0 + srow) * ldw + k0 + sg * 8;
            *(short8*)&Bs[(sg * 64 + srow) * 8] = *(const short8*)srcw;
        }
        __syncthreads();

        short8 a[2], b[2];
        #pragma unroll
        for (int i = 0; i < 2; ++i) {
            a[i] = *(const short8*)&As[(quad * 64 + wm + i * 16 + fr) * 8];
            b[i] = *(const short8*)&Bs[(quad * 64 + wn + i * 16 + fr) * 8];
        }
        #pragma unroll
        for (int im = 0; im < 2; ++im)
            #pragma unroll
            for (int in = 0; in < 2; ++in)
                acc[im][in] = __builtin_amdgcn_mfma_f32_16x16x32_bf16(
                    a[im], b[in], acc[im][in], 0, 0, 0);
    }

    // Epilogue (C/D layout: col=lane&15, row=(lane>>4)*4+reg)
    #pragma unroll
    for (int im = 0; im < 2; ++im) {
        #pragma unroll
        for (int reg = 0; reg < 4; ++reg) {
            const int m = m0 + wm + im * 16 + quad * 4 + reg;
            #pragma unroll
            for (int in = 0; in < 2; ++in) {
                const int n = n0 + wn + in * 16 + fr;
                float v = acc[im][in][reg];
                if (bias) v += bias[n];
                if (relu) v = fmaxf(v, 0.f);
                if (res)  v += bf2f(res[(size_t)m * N + n]);
                C[(size_t)m * N + n] = __float2bfloat16(v);
            }
        }
    }
}

// ---------------------------------------------------------------------------
// LayerNorm over last dim (256), bf16 in/out, fp32 g/b, optional PE.
// ---------------------------------------------------------------------------
__global__ __launch_bounds__(256)
void ln_k(const bf16* in, bf16* out,
          const float* __restrict__ g, const float* __restrict__ b, int use_pe)
{
    __shared__ float red[256];
    const int row = blockIdx.x;
    const int c = threadIdx.x;
    float v = bf2f(in[(size_t)row * D_ + c]);
    if (use_pe) {
        int n = row & (N_ - 1);
        int j = c & ~1;
        float freq = __expf(-(float)j * (9.210340371976184f / 256.0f));
        float ang = (float)n * freq;
        v += (c & 1) ? cosf(ang) : sinf(ang);
    }
    red[c] = v; __syncthreads();
    for (int s = 128; s > 0; s >>= 1) { if (c < s) red[c] += red[c + s]; __syncthreads(); }
    float mu = red[0] * (1.f / 256.f);
    __syncthreads();
    float d = v - mu;
    red[c] = d * d; __syncthreads();
    for (int s = 128; s > 0; s >>= 1) { if (c < s) red[c] += red[c + s]; __syncthreads(); }
    float var = red[0] * (1.f / 256.f);
    float rs = rsqrtf(var + 1e-5f);
    out[(size_t)row * D_ + c] = __float2bfloat16(d * rs * g[c] + b[c]);
}

// ---------------------------------------------------------------------------
// MFMA flash-style cross-attention (unchanged from round 5).
// ---------------------------------------------------------------------------
__global__ __launch_bounds__(256)
void attn_k(const bf16* q, const bf16* __restrict__ k,
            const bf16* __restrict__ v, bf16* ctx)
{
    __shared__ bf16 Qs[8 * 64 * 8];
    __shared__ bf16 Ks[8 * 64 * 8];
    __shared__ bf16 Vs[8 * 64 * 8];
    __shared__ bf16 Ps[4 * 16 * 72];

    const int tid = threadIdx.x;
    const int qt = blockIdx.x & 7;
    const int h  = (blockIdx.x >> 3) & 3;
    const int b  = blockIdx.x >> 5;
    const int q0 = qt * 64;
    const size_t base = ((size_t)b * N_) * D_ + h * HD_;

    const int lane = tid & 63;
    const int w = tid >> 6;
    const int fr = lane & 15, quad = lane >> 4;

    {
        const int row = tid >> 2, c = tid & 3;
        const unsigned short* src = (const unsigned short*)q + base + (size_t)(q0 + row) * D_ + c * 16;
        *(short8*)&Qs[((c * 2 + 0) * 64 + row) * 8] = *(const short8*)(src);
        *(short8*)&Qs[((c * 2 + 1) * 64 + row) * 8] = *(const short8*)(src + 8);
    }
    __syncthreads();

    short8 aq[2];
    #pragma unroll
    for (int ks = 0; ks < 2; ++ks)
        aq[ks] = *(const short8*)&Qs[((ks * 4 + quad) * 64 + w * 16 + fr) * 8];

    floatx4 O[4] = {};
    float mrun[4], lrun[4];
    #pragma unroll
    for (int r = 0; r < 4; ++r) { mrun[r] = -1e30f; lrun[r] = 0.f; }

    for (int kt = 0; kt < 8; ++kt) {
        __syncthreads();
        {
            const int row = tid >> 2, c = tid & 3;
            const unsigned short* srck = (const unsigned short*)k + base + (size_t)(kt * 64 + row) * D_ + c * 16;
            *(short8*)&Ks[((c * 2 + 0) * 64 + row) * 8] = *(const short8*)(srck);
            *(short8*)&Ks[((c * 2 + 1) * 64 + row) * 8] = *(const short8*)(srck + 8);

            const int key = row, gk = key >> 3, jk = key & 7;
            const unsigned short* srcv = (const unsigned short*)v + base + (size_t)(kt * 64 + key) * D_ + c * 16;
            #pragma unroll
            for (int u = 0; u < 4; ++u) {
                ushort4 vv = *(const ushort4*)(srcv + u * 4);
                const int d0 = c * 16 + u * 4;
                Vs[(gk * 64 + d0 + 0) * 8 + jk] = *(bf16*)&vv.x;
                Vs[(gk * 64 + d0 + 1) * 8 + jk] = *(bf16*)&vv.y;
                Vs[(gk * 64 + d0 + 2) * 8 + jk] = *(bf16*)&vv.z;
                Vs[(gk * 64 + d0 + 3) * 8 + jk] = *(bf16*)&vv.w;
            }
        }
        __syncthreads();

        floatx4 S[4] = {};
        #pragma unroll
        for (int in = 0; in < 4; ++in) {
            #pragma unroll
            for (int ks = 0; ks < 2; ++ks) {
                short8 bk = *(const short8*)&Ks[((ks * 4 + quad) * 64 + in * 16 + fr) * 8];
                S[in] = __builtin_amdgcn_mfma_f32_16x16x32_bf16(aq[ks], bk, S[in], 0, 0, 0);
            }
        }
        #pragma unroll
        for (int in = 0; in < 4; ++in) S[in] *= 0.125f;

        #pragma unroll
        for (int r = 0; r < 4; ++r) {
            float mloc = fmaxf(fmaxf(S[0][r], S[1][r]), fmaxf(S[2][r], S[3][r]));
            #pragma unroll
            for (int off = 1; off < 16; off <<= 1) mloc = fmaxf(mloc, __shfl_xor(mloc, off, 64));
            float mnew = fmaxf(mrun[r], mloc);
            float alpha = __expf(mrun[r] - mnew);
            float rs = 0.f;
            #pragma unroll
            for (int in = 0; in < 4; ++in) {
                float p = __expf(S[in][r] - mnew);
                S[in][r] = p;
                rs += p;
            }
            #pragma unroll
            for (int off = 1; off < 16; off <<= 1) rs += __shfl_xor(rs, off, 64);
            lrun[r] = lrun[r] * alpha + rs;
            mrun[r] = mnew;
            #pragma unroll
            for (int in = 0; in < 4; ++in) O[in][r] *= alpha;
        }

        #pragma unroll
        for (int in = 0; in < 4; ++in)
            #pragma unroll
            for (int r = 0; r < 4; ++r)
                Ps[(w * 16 + quad * 4 + r) * 72 + in * 16 + fr] = __float2bfloat16(S[in][r]);
        short8 pa[2];
        #pragma unroll
        for (int ks = 0; ks < 2; ++ks)
            pa[ks] = *(const short8*)&Ps[(w * 16 + fr) * 72 + ks * 32 + quad * 8];

        #pragma unroll
        for (int in = 0; in < 4; ++in) {
            #pragma unroll
            for (int ks = 0; ks < 2; ++ks) {
                short8 bv = *(const short8*)&Vs[((ks * 4 + quad) * 64 + in * 16 + fr) * 8];
                O[in] = __builtin_amdgcn_mfma_f32_16x16x32_bf16(pa[ks], bv, O[in], 0, 0, 0);
            }
        }
    }

    #pragma unroll
    for (int r = 0; r < 4; ++r) {
        const float inv = 1.f / lrun[r];
        const int row = q0 + w * 16 + quad * 4 + r;
        #pragma unroll
        for (int in = 0; in < 4; ++in)
            ctx[base + (size_t)row * D_ + in * 16 + fr] = __float2bfloat16(O[in][r] * inv);
    }
}

// ---------------------------------------------------------------------------
// Mean-pool stage 1: partial sums over 64-row chunks. grid (B, 8), block 256.
// ---------------------------------------------------------------------------
__global__ __launch_bounds__(256)
void pool_k(const bf16* __restrict__ x, float* __restrict__ partial)
{
    int b = blockIdx.x, ch = blockIdx.y, c = threadIdx.x;
    float s = 0.f;
    for (int n = ch * 64; n < ch * 64 + 64; ++n)
        s += bf2f(x[((size_t)b * N_ + n) * D_ + c]);
    partial[((size_t)b * 8 + ch) * D_ + c] = s;
}

// ---------------------------------------------------------------------------
// Mean-pool stage 2 + logits. grid B, block 256. out fp32 (B,2).
// ---------------------------------------------------------------------------
__global__ __launch_bounds__(256)
void logits_k(const float* __restrict__ partial, const float* __restrict__ Wc,
              const float* __restrict__ bc, float* __restrict__ out)
{
    __shared__ float pl[256];
    __shared__ float red[256];
    int b = blockIdx.x, c = threadIdx.x;
    float s = 0.f;
    for (int ch = 0; ch < 8; ++ch) s += partial[((size_t)b * 8 + ch) * D_ + c];
    pl[c] = s * (1.f / 512.f);
    __syncthreads();
    int o = c >> 7, cc = c & 127;
    red[c] = pl[cc] * Wc[o * 256 + cc] + pl[cc + 128] * Wc[o * 256 + cc + 128];
    __syncthreads();
    for (int st = 64; st > 0; st >>= 1) { if (cc < st) red[c] += red[c + st]; __syncthreads(); }
    if (cc == 0) out[b * 2 + o] = red[c] + bc[o];
}

// ---------------------------------------------------------------------------
extern "C" void kernel_launch(void* const* d_in, const int* in_sizes, int n_in,
                              void* d_out, int out_size, void* d_ws, size_t ws_size,
                              hipStream_t stream)
{
    const float* x   = (const float*)d_in[0];
    const float* y   = (const float*)d_in[1];
    // d_in[2] = z, unused by the reference
    const float* Wr  = (const float*)d_in[3];
    const float* br  = (const float*)d_in[4];
    const float* Wf  = (const float*)d_in[5];
    const float* bfv = (const float*)d_in[6];
    const float* gx  = (const float*)d_in[7];
    const float* bx  = (const float*)d_in[8];
    const float* gy  = (const float*)d_in[9];
    const float* by  = (const float*)d_in[10];
    const float* Wq  = (const float*)d_in[11];
    const float* bq  = (const float*)d_in[12];
    const float* Wk  = (const float*)d_in[13];
    const float* bk  = (const float*)d_in[14];
    const float* Wv  = (const float*)d_in[15];
    const float* bv  = (const float*)d_in[16];
    const float* Wo  = (const float*)d_in[17];
    const float* bo  = (const float*)d_in[18];
    const float* gm  = (const float*)d_in[19];
    const float* bm  = (const float*)d_in[20];
    const float* W1  = (const float*)d_in[21];
    const float* b1  = (const float*)d_in[22];
    const float* W2  = (const float*)d_in[23];
    const float* b2  = (const float*)d_in[24];
    const float* Wc  = (const float*)d_in[25];
    const float* bc  = (const float*)d_in[26];

    bf16* ws = (bf16*)d_ws;
    const size_t S = (size_t)B_ * N_ * D_;   // 8,388,608 elements per buffer
    bf16* bA = ws;                            // xp
    bf16* bB = ws + S;                        // yp -> x_mlp
    bf16* bC = ws + 2 * S;                    // q -> ctx (in-place)
    bf16* bD = ws + 3 * S;                    // k -> x_res
    bf16* bE = ws + 4 * S;                    // v -> mlp hidden
    bf16* wb = ws + 5 * S;                    // converted weights (778,240 elems)
    float* part = (float*)(wb + 778240);      // 64*8*256 fp32 partials

    bf16* Wrb = wb;                           // 256 x 800
    bf16* Wfb = wb + 256 * 800;               // 256 x 704
    bf16* Wqb = wb + 256 * 800 + 256 * 704;   // 6 x (256 x 256)
    bf16* Wkb = Wqb + 65536;
    bf16* Wvb = Wkb + 65536;
    bf16* Wvb2= Wvb + 65536;   // Wo
    bf16* W1b = Wvb2 + 65536;
    bf16* W2b = W1b + 65536;

    const int M = B_ * N_; // 32768 rows
    dim3 blk(256);
    dim3 g64(M / 64, D_ / 64);                // 512 x 4 = 2048 blocks

    // 0) convert + pad all weights to bf16
    convw_k<<<dim3(100, 8), blk, 0, stream>>>(Wr, Wf, Wq, Wk, Wv, Wo, W1, W2, wb);

    // xp = LN(x @ Wr.T + br + pe)
    gemm64<1><<<g64, blk, 0, stream>>>(x, 769, Wrb, 800, br, nullptr, bA, M, D_, 800, 769, 0);
    ln_k<<<M, blk, 0, stream>>>(bA, bA, gx, bx, 1);
    // yp = LN(y @ Wf.T + bf + pe)
    gemm64<1><<<g64, blk, 0, stream>>>(y, 674, Wfb, 704, bfv, nullptr, bB, M, D_, 704, 674, 0);
    ln_k<<<M, blk, 0, stream>>>(bB, bB, gy, by, 1);
    // q,k,v
    gemm64<0><<<g64, blk, 0, stream>>>(bA, 256, Wqb, 256, bq, nullptr, bC, M, D_, 256, 256, 0);
    gemm64<0><<<g64, blk, 0, stream>>>(bB, 256, Wkb, 256, bk, nullptr, bD, M, D_, 256, 256, 0);
    gemm64<0><<<g64, blk, 0, stream>>>(bB, 256, Wvb, 256, bv, nullptr, bE, M, D_, 256, 256, 0);
    // attention -> ctx (in-place over q)
    attn_k<<<B_ * H_ * 8, blk, 0, stream>>>(bC, bD, bE, bC);
    // x_res = LN(xp + ctx @ Wo.T + bo)
    gemm64<0><<<g64, blk, 0, stream>>>(bC, 256, Wvb2, 256, bo, bA, bD, M, D_, 256, 256, 0);
    ln_k<<<M, blk, 0, stream>>>(bD, bD, gm, bm, 0);
    // mlp
    gemm64<0><<<g64, blk, 0, stream>>>(bD, 256, W1b, 256, b1, nullptr, bE, M, D_, 256, 256, 1);
    gemm64<0><<<g64, blk, 0, stream>>>(bE, 256, W2b, 256, b2, bD, bB, M, D_, 256, 256, 0);
    // mean-pool + logits
    pool_k<<<dim3(B_, 8), blk, 0, stream>>>(bB, part);
    logits_k<<<B_, blk, 0, stream>>>(part, Wc, bc, (float*)d_out);
}

// Round 7
// 715.527 us; speedup vs baseline: 2.6293x; 1.4877x over previous
//
#include <hip/hip_runtime.h>
#include <hip/hip_bf16.h>

// Problem constants
#define B_   64
#define N_   512
#define D_   256
#define H_   4
#define HD_  64

typedef __hip_bfloat16 bf16;
typedef __attribute__((ext_vector_type(8))) short short8;
typedef __attribute__((ext_vector_type(4))) float floatx4;

__device__ __forceinline__ float bf2f(bf16 v) { return __bfloat162float(v); }
__device__ __forceinline__ unsigned short f2us(float f) {
    bf16 h = __float2bfloat16(f);
    union { bf16 h; unsigned short u; } c; c.h = h; return c.u;
}

// async 16B global -> LDS DMA (gfx950). LDS dest must be wave-uniform base +
// lane*16 -- our per-lane pointers are lane-contiguous by construction.
typedef __attribute__((address_space(1))) const unsigned int asg_u32;
typedef __attribute__((address_space(3))) unsigned int asl_u32;
__device__ __forceinline__ void gl_lds16(const void* g, void* l) {
    __builtin_amdgcn_global_load_lds((asg_u32*)g, (asl_u32*)l, 16, 0, 0);
}

// ---------------------------------------------------------------------------
// Weight pre-convert: fp32 -> bf16, zero-padded rows Kreal -> Kp (K%32==0).
// dst layout: Wr[256*800] Wf[256*704] Wq Wk Wv Wo W1 W2 [256*256 each].
// ---------------------------------------------------------------------------
__global__ __launch_bounds__(256)
void convw_k(const float* __restrict__ Wr, const float* __restrict__ Wf,
             const float* __restrict__ Wq, const float* __restrict__ Wk,
             const float* __restrict__ Wv, const float* __restrict__ Wo,
             const float* __restrict__ W1, const float* __restrict__ W2,
             bf16* __restrict__ dst)
{
    const int seg = blockIdx.y;
    const float* src; int Kreal, Kp; size_t off;
    switch (seg) {
        case 0: src = Wr; Kreal = 769; Kp = 800; off = 0; break;
        case 1: src = Wf; Kreal = 674; Kp = 704; off = 256 * 800; break;
        default:
            src = (seg == 2) ? Wq : (seg == 3) ? Wk : (seg == 4) ? Wv
                : (seg == 5) ? Wo : (seg == 6) ? W1 : W2;
            Kreal = 256; Kp = 256;
            off = 256 * 800 + 256 * 704 + (size_t)(seg - 2) * 256 * 256;
            break;
    }
    const int idx = blockIdx.x * 256 + threadIdx.x;   // unit = 8 outputs
    if (idx >= 256 * Kp / 8) return;
    const int rowk = idx * 8;
    const int n = rowk / Kp, k0 = rowk % Kp;
    unsigned short tmp[8];
    #pragma unroll
    for (int j = 0; j < 8; ++j) {
        int kk = k0 + j;
        tmp[j] = f2us(kk < Kreal ? src[(size_t)n * Kreal + kk] : 0.f);
    }
    *(short8*)&dst[off + (size_t)rowk] = *(short8*)tmp;
}

// ---------------------------------------------------------------------------
// Activation convert: fp32 (rows x Kreal) -> bf16 (rows x Kp), zero-padded.
// One block per row; fully coalesced reads and writes. grid = 32768.
// ---------------------------------------------------------------------------
__global__ __launch_bounds__(256)
void convx_k(const float* __restrict__ src, bf16* __restrict__ dst,
             int Kreal, int Kp)
{
    const int row = blockIdx.x;
    const float* s = src + (size_t)row * Kreal;
    bf16* d = dst + (size_t)row * Kp;
    for (int c = threadIdx.x; c < Kp; c += 256)
        d[c] = __float2bfloat16(c < Kreal ? s[c] : 0.f);
}

// ---------------------------------------------------------------------------
// Positional-embedding table: pe[n][c], n<512, c<256. grid 512 x 256 thr.
// ---------------------------------------------------------------------------
__global__ __launch_bounds__(256)
void pe_k(float* __restrict__ pe)
{
    const int n = blockIdx.x, c = threadIdx.x;
    const int j = c & ~1;
    float freq = __expf(-(float)j * (9.210340371976184f / 256.0f)); // ln(10000)/d
    float ang = (float)n * freq;
    pe[n * 256 + c] = (c & 1) ? cosf(ang) : sinf(ang);
}

// ---------------------------------------------------------------------------
// MFMA GEMM, 64x64 tile, BK=32, all-bf16 inputs, fp32 accum, bf16 out.
// Staging: global_load_lds width=16 (2 DMA per thread per k-iter).
// LDS k-group-major [g][row][8]; frag ds_read_b128 conflict-free.
// Requires: lda/ldw elems * 2B % 16 == 0 (true for 800/704/256), Kp%32==0.
// ---------------------------------------------------------------------------
__global__ __launch_bounds__(256)
void gemm64(const bf16* __restrict__ A, int lda,
            const bf16* __restrict__ W, int ldw,
            const float* __restrict__ bias, const bf16* __restrict__ res,
            bf16* __restrict__ C, int M, int N, int Kp, int relu)
{
    __shared__ bf16 As[4 * 64 * 8];
    __shared__ bf16 Bs[4 * 64 * 8];

    const int tid = threadIdx.x;
    const int m0 = blockIdx.x * 64;
    const int n0 = blockIdx.y * 64;
    const int lane = tid & 63;
    const int w = tid >> 6;
    const int wm = (w & 1) * 32, wn = (w >> 1) * 32;
    const int fr = lane & 15, quad = lane >> 4;

    // wave w stages k-col-group w; lane = row. LDS dst contiguous in lane.
    const unsigned short* Ap = (const unsigned short*)A + (size_t)(m0 + lane) * lda + w * 8;
    const unsigned short* Wp = (const unsigned short*)W + (size_t)(n0 + lane) * ldw + w * 8;
    bf16* AsDst = &As[((w * 64) + lane) * 8];
    bf16* BsDst = &Bs[((w * 64) + lane) * 8];

    floatx4 acc[2][2] = {};

    for (int k0 = 0; k0 < Kp; k0 += 32) {
        __syncthreads();                 // previous tile's reads complete
        gl_lds16(Ap + k0, AsDst);
        gl_lds16(Wp + k0, BsDst);
        __syncthreads();                 // vmcnt(0) drains DMA before reads

        short8 a[2], b[2];
        #pragma unroll
        for (int i = 0; i < 2; ++i) {
            a[i] = *(const short8*)&As[(quad * 64 + wm + i * 16 + fr) * 8];
            b[i] = *(const short8*)&Bs[(quad * 64 + wn + i * 16 + fr) * 8];
        }
        #pragma unroll
        for (int im = 0; im < 2; ++im)
            #pragma unroll
            for (int in = 0; in < 2; ++in)
                acc[im][in] = __builtin_amdgcn_mfma_f32_16x16x32_bf16(
                    a[im], b[in], acc[im][in], 0, 0, 0);
    }

    // Epilogue (C/D layout: col=lane&15, row=(lane>>4)*4+reg)
    #pragma unroll
    for (int im = 0; im < 2; ++im) {
        #pragma unroll
        for (int reg = 0; reg < 4; ++reg) {
            const int m = m0 + wm + im * 16 + quad * 4 + reg;
            #pragma unroll
            for (int in = 0; in < 2; ++in) {
                const int n = n0 + wn + in * 16 + fr;
                float v = acc[im][in][reg];
                if (bias) v += bias[n];
                if (relu) v = fmaxf(v, 0.f);
                if (res)  v += bf2f(res[(size_t)m * N + n]);
                C[(size_t)m * N + n] = __float2bfloat16(v);
            }
        }
    }
}

// ---------------------------------------------------------------------------
// LayerNorm over last dim (256), bf16 in/out, fp32 g/b, optional PE table.
// Wave-shuffle reductions; 2 barriers total.
// ---------------------------------------------------------------------------
__global__ __launch_bounds__(256)
void ln_k(const bf16* in, bf16* out,
          const float* __restrict__ g, const float* __restrict__ b,
          const float* __restrict__ pe)
{
    __shared__ float sm[4], sm2[4];
    const int row = blockIdx.x, c = threadIdx.x;
    const int lane = c & 63, w = c >> 6;
    float v = bf2f(in[(size_t)row * D_ + c]);
    if (pe) v += pe[(row & (N_ - 1)) * D_ + c];
    float s = v;
    #pragma unroll
    for (int off = 32; off > 0; off >>= 1) s += __shfl_xor(s, off, 64);
    if (lane == 0) sm[w] = s;
    __syncthreads();
    float mu = (sm[0] + sm[1] + sm[2] + sm[3]) * (1.f / 256.f);
    float d = v - mu;
    float s2 = d * d;
    #pragma unroll
    for (int off = 32; off > 0; off >>= 1) s2 += __shfl_xor(s2, off, 64);
    if (lane == 0) sm2[w] = s2;
    __syncthreads();
    float var = (sm2[0] + sm2[1] + sm2[2] + sm2[3]) * (1.f / 256.f);
    float rs = rsqrtf(var + 1e-5f);
    out[(size_t)row * D_ + c] = __float2bfloat16(d * rs * g[c] + b[c]);
}

// ---------------------------------------------------------------------------
// MFMA flash-style cross-attention (unchanged from round 5).
// ---------------------------------------------------------------------------
__global__ __launch_bounds__(256)
void attn_k(const bf16* q, const bf16* __restrict__ k,
            const bf16* __restrict__ v, bf16* ctx)
{
    __shared__ bf16 Qs[8 * 64 * 8];
    __shared__ bf16 Ks[8 * 64 * 8];
    __shared__ bf16 Vs[8 * 64 * 8];
    __shared__ bf16 Ps[4 * 16 * 72];

    const int tid = threadIdx.x;
    const int qt = blockIdx.x & 7;
    const int h  = (blockIdx.x >> 3) & 3;
    const int b  = blockIdx.x >> 5;
    const int q0 = qt * 64;
    const size_t base = ((size_t)b * N_) * D_ + h * HD_;

    const int lane = tid & 63;
    const int w = tid >> 6;
    const int fr = lane & 15, quad = lane >> 4;

    {
        const int row = tid >> 2, c = tid & 3;
        const unsigned short* src = (const unsigned short*)q + base + (size_t)(q0 + row) * D_ + c * 16;
        *(short8*)&Qs[((c * 2 + 0) * 64 + row) * 8] = *(const short8*)(src);
        *(short8*)&Qs[((c * 2 + 1) * 64 + row) * 8] = *(const short8*)(src + 8);
    }
    __syncthreads();

    short8 aq[2];
    #pragma unroll
    for (int ks = 0; ks < 2; ++ks)
        aq[ks] = *(const short8*)&Qs[((ks * 4 + quad) * 64 + w * 16 + fr) * 8];

    floatx4 O[4] = {};
    float mrun[4], lrun[4];
    #pragma unroll
    for (int r = 0; r < 4; ++r) { mrun[r] = -1e30f; lrun[r] = 0.f; }

    for (int kt = 0; kt < 8; ++kt) {
        __syncthreads();
        {
            const int row = tid >> 2, c = tid & 3;
            const unsigned short* srck = (const unsigned short*)k + base + (size_t)(kt * 64 + row) * D_ + c * 16;
            *(short8*)&Ks[((c * 2 + 0) * 64 + row) * 8] = *(const short8*)(srck);
            *(short8*)&Ks[((c * 2 + 1) * 64 + row) * 8] = *(const short8*)(srck + 8);

            const int key = row, gk = key >> 3, jk = key & 7;
            const unsigned short* srcv = (const unsigned short*)v + base + (size_t)(kt * 64 + key) * D_ + c * 16;
            #pragma unroll
            for (int u = 0; u < 4; ++u) {
                ushort4 vv = *(const ushort4*)(srcv + u * 4);
                const int d0 = c * 16 + u * 4;
                Vs[(gk * 64 + d0 + 0) * 8 + jk] = *(bf16*)&vv.x;
                Vs[(gk * 64 + d0 + 1) * 8 + jk] = *(bf16*)&vv.y;
                Vs[(gk * 64 + d0 + 2) * 8 + jk] = *(bf16*)&vv.z;
                Vs[(gk * 64 + d0 + 3) * 8 + jk] = *(bf16*)&vv.w;
            }
        }
        __syncthreads();

        floatx4 S[4] = {};
        #pragma unroll
        for (int in = 0; in < 4; ++in) {
            #pragma unroll
            for (int ks = 0; ks < 2; ++ks) {
                short8 bk = *(const short8*)&Ks[((ks * 4 + quad) * 64 + in * 16 + fr) * 8];
                S[in] = __builtin_amdgcn_mfma_f32_16x16x32_bf16(aq[ks], bk, S[in], 0, 0, 0);
            }
        }
        #pragma unroll
        for (int in = 0; in < 4; ++in) S[in] *= 0.125f;

        #pragma unroll
        for (int r = 0; r < 4; ++r) {
            float mloc = fmaxf(fmaxf(S[0][r], S[1][r]), fmaxf(S[2][r], S[3][r]));
            #pragma unroll
            for (int off = 1; off < 16; off <<= 1) mloc = fmaxf(mloc, __shfl_xor(mloc, off, 64));
            float mnew = fmaxf(mrun[r], mloc);
            float alpha = __expf(mrun[r] - mnew);
            float rs = 0.f;
            #pragma unroll
            for (int in = 0; in < 4; ++in) {
                float p = __expf(S[in][r] - mnew);
                S[in][r] = p;
                rs += p;
            }
            #pragma unroll
            for (int off = 1; off < 16; off <<= 1) rs += __shfl_xor(rs, off, 64);
            lrun[r] = lrun[r] * alpha + rs;
            mrun[r] = mnew;
            #pragma unroll
            for (int in = 0; in < 4; ++in) O[in][r] *= alpha;
        }

        #pragma unroll
        for (int in = 0; in < 4; ++in)
            #pragma unroll
            for (int r = 0; r < 4; ++r)
                Ps[(w * 16 + quad * 4 + r) * 72 + in * 16 + fr] = __float2bfloat16(S[in][r]);
        short8 pa[2];
        #pragma unroll
        for (int ks = 0; ks < 2; ++ks)
            pa[ks] = *(const short8*)&Ps[(w * 16 + fr) * 72 + ks * 32 + quad * 8];

        #pragma unroll
        for (int in = 0; in < 4; ++in) {
            #pragma unroll
            for (int ks = 0; ks < 2; ++ks) {
                short8 bv = *(const short8*)&Vs[((ks * 4 + quad) * 64 + in * 16 + fr) * 8];
                O[in] = __builtin_amdgcn_mfma_f32_16x16x32_bf16(pa[ks], bv, O[in], 0, 0, 0);
            }
        }
    }

    #pragma unroll
    for (int r = 0; r < 4; ++r) {
        const float inv = 1.f / lrun[r];
        const int row = q0 + w * 16 + quad * 4 + r;
        #pragma unroll
        for (int in = 0; in < 4; ++in)
            ctx[base + (size_t)row * D_ + in * 16 + fr] = __float2bfloat16(O[in][r] * inv);
    }
}

// ---------------------------------------------------------------------------
// Mean-pool stage 1: partial sums over 64-row chunks. grid (B, 8), block 256.
// ---------------------------------------------------------------------------
__global__ __launch_bounds__(256)
void pool_k(const bf16* __restrict__ x, float* __restrict__ partial)
{
    int b = blockIdx.x, ch = blockIdx.y, c = threadIdx.x;
    float s = 0.f;
    for (int n = ch * 64; n < ch * 64 + 64; ++n)
        s += bf2f(x[((size_t)b * N_ + n) * D_ + c]);
    partial[((size_t)b * 8 + ch) * D_ + c] = s;
}

// ---------------------------------------------------------------------------
// Mean-pool stage 2 + logits. grid B, block 256. out fp32 (B,2).
// ---------------------------------------------------------------------------
__global__ __launch_bounds__(256)
void logits_k(const float* __restrict__ partial, const float* __restrict__ Wc,
              const float* __restrict__ bc, float* __restrict__ out)
{
    __shared__ float pl[256];
    __shared__ float red[256];
    int b = blockIdx.x, c = threadIdx.x;
    float s = 0.f;
    for (int ch = 0; ch < 8; ++ch) s += partial[((size_t)b * 8 + ch) * D_ + c];
    pl[c] = s * (1.f / 512.f);
    __syncthreads();
    int o = c >> 7, cc = c & 127;
    red[c] = pl[cc] * Wc[o * 256 + cc] + pl[cc + 128] * Wc[o * 256 + cc + 128];
    __syncthreads();
    for (int st = 64; st > 0; st >>= 1) { if (cc < st) red[c] += red[c + st]; __syncthreads(); }
    if (cc == 0) out[b * 2 + o] = red[c] + bc[o];
}

// ---------------------------------------------------------------------------
extern "C" void kernel_launch(void* const* d_in, const int* in_sizes, int n_in,
                              void* d_out, int out_size, void* d_ws, size_t ws_size,
                              hipStream_t stream)
{
    const float* x   = (const float*)d_in[0];
    const float* y   = (const float*)d_in[1];
    // d_in[2] = z, unused by the reference
    const float* Wr  = (const float*)d_in[3];
    const float* br  = (const float*)d_in[4];
    const float* Wf  = (const float*)d_in[5];
    const float* bfv = (const float*)d_in[6];
    const float* gx  = (const float*)d_in[7];
    const float* bx  = (const float*)d_in[8];
    const float* gy  = (const float*)d_in[9];
    const float* by  = (const float*)d_in[10];
    const float* Wq  = (const float*)d_in[11];
    const float* bq  = (const float*)d_in[12];
    const float* Wk  = (const float*)d_in[13];
    const float* bk  = (const float*)d_in[14];
    const float* Wv  = (const float*)d_in[15];
    const float* bv  = (const float*)d_in[16];
    const float* Wo  = (const float*)d_in[17];
    const float* bo  = (const float*)d_in[18];
    const float* gm  = (const float*)d_in[19];
    const float* bm  = (const float*)d_in[20];
    const float* W1  = (const float*)d_in[21];
    const float* b1  = (const float*)d_in[22];
    const float* W2  = (const float*)d_in[23];
    const float* b2  = (const float*)d_in[24];
    const float* Wc  = (const float*)d_in[25];
    const float* bc  = (const float*)d_in[26];

    bf16* ws = (bf16*)d_ws;
    const size_t S = (size_t)B_ * N_ * D_;          // 8,388,608 elems
    bf16*  wb   = ws;                                // weights: 778,240 elems
    float* pe   = (float*)(ws + 778240);             // 131,072 floats
    float* part = pe + 131072;                       // 131,072 floats
    bf16*  bA   = ws + 778240 + 4 * 131072;          // +524,288 elems
    bf16*  bB   = bA + S;
    bf16*  bC   = bB + S;                            // q -> ctx (in-place)
    bf16*  bD   = bC + S;                            // k -> x_res
    bf16*  bE   = bD + S;                            // v -> mlp hidden
    bf16*  xyb  = bC;   // transient padded x/y (26.2M elems, spills past bE)

    bf16* Wrb = wb;                                  // 256 x 800
    bf16* Wfb = wb + 256 * 800;                      // 256 x 704
    bf16* Wqb = Wfb + 256 * 704;
    bf16* Wkb = Wqb + 65536;
    bf16* Wvb = Wkb + 65536;
    bf16* Wob = Wvb + 65536;
    bf16* W1b = Wob + 65536;
    bf16* W2b = W1b + 65536;

    const int M = B_ * N_; // 32768 rows
    dim3 blk(256);
    dim3 g64(M / 64, D_ / 64);                       // 512 x 4 = 2048 blocks

    // 0) constants: PE table + weight conversion
    pe_k<<<N_, blk, 0, stream>>>(pe);
    convw_k<<<dim3(100, 8), blk, 0, stream>>>(Wr, Wf, Wq, Wk, Wv, Wo, W1, W2, wb);

    // xp = LN(x @ Wr.T + br + pe)
    convx_k<<<M, blk, 0, stream>>>(x, xyb, 769, 800);
    gemm64<<<g64, blk, 0, stream>>>(xyb, 800, Wrb, 800, br, nullptr, bA, M, D_, 800, 0);
    ln_k<<<M, blk, 0, stream>>>(bA, bA, gx, bx, pe);
    // yp = LN(y @ Wf.T + bf + pe)
    convx_k<<<M, blk, 0, stream>>>(y, xyb, 674, 704);
    gemm64<<<g64, blk, 0, stream>>>(xyb, 704, Wfb, 704, bfv, nullptr, bB, M, D_, 704, 0);
    ln_k<<<M, blk, 0, stream>>>(bB, bB, gy, by, pe);
    // q,k,v
    gemm64<<<g64, blk, 0, stream>>>(bA, 256, Wqb, 256, bq, nullptr, bC, M, D_, 256, 0);
    gemm64<<<g64, blk, 0, stream>>>(bB, 256, Wkb, 256, bk, nullptr, bD, M, D_, 256, 0);
    gemm64<<<g64, blk, 0, stream>>>(bB, 256, Wvb, 256, bv, nullptr, bE, M, D_, 256, 0);
    // attention -> ctx (in-place over q)
    attn_k<<<B_ * H_ * 8, blk, 0, stream>>>(bC, bD, bE, bC);
    // x_res = LN(xp + ctx @ Wo.T + bo)
    gemm64<<<g64, blk, 0, stream>>>(bC, 256, Wob, 256, bo, bA, bD, M, D_, 256, 0);
    ln_k<<<M, blk, 0, stream>>>(bD, bD, gm, bm, nullptr);
    // mlp
    gemm64<<<g64, blk, 0, stream>>>(bD, 256, W1b, 256, b1, nullptr, bE, M, D_, 256, 1);
    gemm64<<<g64, blk, 0, stream>>>(bE, 256, W2b, 256, b2, bD, bB, M, D_, 256, 0);
    // mean-pool + logits
    pool_k<<<dim3(B_, 8), blk, 0, stream>>>(bB, part);
    logits_k<<<B_, blk, 0, stream>>>(part, Wc, bc, (float*)d_out);
}